// Round 24
// baseline (88.740 us; speedup 1.0000x reference)
//
#include <hip/hip_runtime.h>
#include <hip/hip_bf16.h>

#define SEQ 2048
#define HD 128
#define NH 32
#define NKV 8
#define ODIM 4096
#define QB 64
#define KVB 64
#define SCALE 0.08838834764831845f
#define SCALE_L2E 0.12752767f   /* SCALE * log2(e) */
#define NEGBIG -1e9f
#define NEGBIG_L2 -1.4426950e9f
#define THR_L2 11.54f

typedef __attribute__((ext_vector_type(8))) short bf16x8;
typedef __attribute__((ext_vector_type(4))) float f32x4;
typedef __attribute__((ext_vector_type(16))) float f32x16;
typedef __attribute__((ext_vector_type(2))) int i32x2;

__device__ __forceinline__ unsigned short f2bf(float x) {
  union { __hip_bfloat16 b; unsigned short u; } c;
  c.b = __float2bfloat16(x);
  return c.u;
}

__device__ __forceinline__ unsigned pack2bf(float lo, float hi) {
  union { __hip_bfloat162 h; unsigned u; } c;
  c.h = __float22bfloat162_rn(float2{lo, hi});
  return c.u;
}

__device__ __forceinline__ void gload_lds16(const unsigned char* g, unsigned char* l) {
  __builtin_amdgcn_global_load_lds(
      (const __attribute__((address_space(1))) void*)g,
      (__attribute__((address_space(3))) void*)l, 16, 0, 0);
}

// ---------- prepass (identical to r13..r23): K/V f32 -> pre-swizzled bf16 images ----------
#define KWORK (NKV * SEQ * 16)
#define VWORK (NKV * (SEQ / 2) * 16)
__global__ __launch_bounds__(256) void sdpa_prepass(
    const float* __restrict__ k, const float* __restrict__ v,
    unsigned char* __restrict__ ws) {
  unsigned char* kimg = ws;
  unsigned char* vimg = ws + (NKV * 32 * 16384);
  int idx = (int)blockIdx.x * 256 + (int)threadIdx.x;
  if (idx < KWORK) {
    int hkv = idx >> 15;
    int rem = idx & 32767;
    int rg = rem >> 4;
    int c8 = (rem & 15) << 3;
    const float* src = k + ((size_t)hkv * SEQ + rg) * HD + c8;
    float4 a = *(const float4*)(src);
    float4 b = *(const float4*)(src + 4);
    union { unsigned short hh[8]; uint4 u4; } pk;
    pk.hh[0]=f2bf(a.x); pk.hh[1]=f2bf(a.y); pk.hh[2]=f2bf(a.z); pk.hh[3]=f2bf(a.w);
    pk.hh[4]=f2bf(b.x); pk.hh[5]=f2bf(b.y); pk.hh[6]=f2bf(b.z); pk.hh[7]=f2bf(b.w);
    int t = rg >> 6, r = rg & 63;
    size_t base = ((size_t)(hkv * 32 + t)) << 14;
    *(uint4*)(kimg + base + (r << 8) + ((c8 << 1) ^ ((r & 7) << 4))) = pk.u4;
  } else {
    int u = idx - KWORK;
    if (u >= VWORK) return;
    int hkv = u >> 14;
    int rem = u & 16383;
    int pr = rem >> 4;
    int d0 = (rem & 15) << 3;
    int rg = pr << 1;
    const float* s0 = v + ((size_t)hkv * SEQ + rg) * HD + d0;
    const float* s1 = s0 + HD;
    float4 a0 = *(const float4*)(s0);
    float4 b0 = *(const float4*)(s0 + 4);
    float4 a1 = *(const float4*)(s1);
    float4 b1 = *(const float4*)(s1 + 4);
    float lo[8] = {a0.x,a0.y,a0.z,a0.w,b0.x,b0.y,b0.z,b0.w};
    float hi[8] = {a1.x,a1.y,a1.z,a1.w,b1.x,b1.y,b1.z,b1.w};
    int t = rg >> 6, rr = rg & 63;
    size_t base = ((size_t)(hkv * 32 + t)) << 14;
    int rb = rr << 1;
    #pragma unroll
    for (int j = 0; j < 8; ++j) {
      int d = d0 + j;
      *(unsigned*)(vimg + base + (d << 7) + (rb ^ ((d & 7) << 4))) =
          pack2bf(lo[j], hi[j]);
    }
  }
}

// ---------- main: r14's 32x32 compute body + r20's 3-slot rotation schedule ----------
// Block = 256 thr (4 waves), pair {p, 31-p}: waves 0,1 -> tile A 32-row
// strips; waves 2,3 -> tile B. Per tile: STAGE_K(t+1)->sC ; QK(2 kv-blocks x
// 8 K-steps of 32x32x16) + mask + softmax + permlane P-build (reg-only) ;
// barrier1 ; STAGE_V(t+1)->sA ; PV(4 d-blocks x 4 K-steps) ; barrier2 ;
// rotate. LDS 48KB -> 3 blocks/CU if VGPR allows ~3 waves/SIMD (~12 waves/CU).
__global__ __launch_bounds__(256, 2) void sdpa_flash_kernel(
    const float* __restrict__ q, const unsigned char* __restrict__ kimg,
    const unsigned char* __restrict__ vimg, float* __restrict__ out) {
  __shared__ __align__(16) unsigned char smem[49152];
  const int tid = threadIdx.x;
  const int w = tid >> 6;        // 0..3
  const int l = tid & 63;
  const int q31 = l & 31;
  const int hi = l >> 5;

  const int p = (int)blockIdx.x;       // 0..15
  const int qtA = p, qtB = 31 - p;
  const int myqt = (w < 2) ? qtA : qtB;
  const int h = (int)blockIdx.y;
  const int hkv = h >> 2;
  const int qbase = myqt * QB + 32 * (w & 1);
  const int myq = qbase + q31;         // this lane's q row

  // ---- Q fragments: qa[s] = Q[myq][d = 16s + 8hi + j], pre-scaled by SCALE*log2e ----
  bf16x8 qa[8];
  {
    const float* qr = q + ((size_t)(h * SEQ + myq)) * HD + 8 * hi;
    #pragma unroll
    for (int s = 0; s < 8; ++s) {
      float4 a = *(const float4*)(qr + 16 * s);
      float4 b = *(const float4*)(qr + 16 * s + 4);
      union { unsigned short hh[8]; bf16x8 vv; } pk;
      pk.hh[0] = f2bf(a.x * SCALE_L2E); pk.hh[1] = f2bf(a.y * SCALE_L2E);
      pk.hh[2] = f2bf(a.z * SCALE_L2E); pk.hh[3] = f2bf(a.w * SCALE_L2E);
      pk.hh[4] = f2bf(b.x * SCALE_L2E); pk.hh[5] = f2bf(b.y * SCALE_L2E);
      pk.hh[6] = f2bf(b.z * SCALE_L2E); pk.hh[7] = f2bf(b.w * SCALE_L2E);
      qa[s] = pk.vv;
    }
  }

  // O^T accumulators: o[db] reg r = O[d = 32db + (r&3)+8(r>>2)+4hi][q=myq]
  f32x16 o[4];
  #pragma unroll
  for (int db = 0; db < 4; ++db)
    #pragma unroll
    for (int r = 0; r < 16; ++r) o[db][r] = 0.f;
  float mrow = -1e30f, lrow = 0.f;

  const int ntiles = qtB + 1;
  const unsigned char* kt0 = kimg + (((size_t)(hkv * 32)) << 14);
  const unsigned char* vt0 = vimg + (((size_t)(hkv * 32)) << 14);
  const int woff = w << 12;  // wave's 4KB slice of each 16KB tile

#define STAGE_K(tt, Kb) {                                                    \
    const unsigned char* ks_ = kt0 + (((size_t)(tt)) << 14) + woff + (l << 4); \
    unsigned char* kd_ = (Kb) + woff;                                        \
    gload_lds16(ks_, kd_);                                                   \
    gload_lds16(ks_ + 1024, kd_ + 1024);                                     \
    gload_lds16(ks_ + 2048, kd_ + 2048);                                     \
    gload_lds16(ks_ + 3072, kd_ + 3072);                                     \
  }
#define STAGE_V(tt, Vb) {                                                    \
    const unsigned char* vs_ = vt0 + (((size_t)(tt)) << 14) + woff + (l << 4); \
    unsigned char* vd_ = (Vb) + woff;                                        \
    gload_lds16(vs_, vd_);                                                   \
    gload_lds16(vs_ + 1024, vd_ + 1024);                                     \
    gload_lds16(vs_ + 2048, vd_ + 2048);                                     \
    gload_lds16(vs_ + 3072, vd_ + 3072);                                     \
  }

  unsigned char* sA = smem;            // K(t)
  unsigned char* sB = smem + 16384;    // V(t)
  unsigned char* sC = smem + 32768;    // free / incoming K(t+1)

  STAGE_K(0, sA);
  STAGE_V(0, sB);
  __syncthreads();

  for (int t = 0; t < ntiles; ++t) {
    const int kv0 = t * KVB;
    const bool have_next = (t + 1 < ntiles);
    if (have_next) STAGE_K(t + 1, sC);

    const bool act = (t <= myqt);      // wave-uniform
    bf16x8 pf[4];
    if (act) {
      // ---- S^T = K Q^T: 2 kv-blocks x 8 K-steps of 32x32x16 (r14-verified) ----
      f32x16 s0, s1;
      #pragma unroll
      for (int r = 0; r < 16; ++r) { s0[r] = 0.f; s1[r] = 0.f; }
      __builtin_amdgcn_s_setprio(1);
      #pragma unroll
      for (int s = 0; s < 8; ++s) {
        int colb = 32 * s + 16 * hi;
        int r0 = q31;
        bf16x8 k0 = *(const bf16x8*)(sA + (r0 << 8) + (colb ^ ((r0 & 7) << 4)));
        int r1 = 32 + q31;
        bf16x8 k1 = *(const bf16x8*)(sA + (r1 << 8) + (colb ^ ((r1 & 7) << 4)));
        s0 = __builtin_amdgcn_mfma_f32_32x32x16_bf16(k0, qa[s], s0, 0, 0, 0);
        s1 = __builtin_amdgcn_mfma_f32_32x32x16_bf16(k1, qa[s], s1, 0, 0, 0);
      }
      __builtin_amdgcn_s_setprio(0);

      // ---- causal mask (diagonal tile only; r14-verified mapping) ----
      if (t == myqt) {
        #pragma unroll
        for (int r = 0; r < 16; ++r) {
          int kvr = kv0 + (r & 3) + 8 * (r >> 2) + 4 * hi;
          s0[r] += (kvr > myq) ? NEGBIG_L2 : 0.f;
          s1[r] += (kvr + 32 > myq) ? NEGBIG_L2 : 0.f;
        }
      }

      // ---- online softmax: lane pair {l, l^32} shares row q=myq ----
      float tm = -1e30f;
      #pragma unroll
      for (int r = 0; r < 16; ++r) {
        tm = fmaxf(tm, s0[r]);
        tm = fmaxf(tm, s1[r]);
      }
      tm = fmaxf(tm, __shfl_xor(tm, 32));
      if (!__all(tm <= mrow + THR_L2)) {  // defer-max
        float mn = fmaxf(mrow, tm);
        float fac = __builtin_amdgcn_exp2f(mrow - mn);
        mrow = mn;
        lrow *= fac;
        #pragma unroll
        for (int db = 0; db < 4; ++db)
          #pragma unroll
          for (int r = 0; r < 16; ++r) o[db][r] *= fac;
      }
      float rs = 0.f;
      #pragma unroll
      for (int r = 0; r < 16; ++r) {
        s0[r] = __builtin_amdgcn_exp2f(s0[r] - mrow); rs += s0[r];
        s1[r] = __builtin_amdgcn_exp2f(s1[r] - mrow); rs += s1[r];
      }
      rs += __shfl_xor(rs, 32);
      lrow += rs;

      // ---- PV B-frags: pack + permlane32_swap (r14-verified layout) ----
      #pragma unroll
      for (int s2 = 0; s2 < 2; ++s2) {
        {
          unsigned a0 = pack2bf(s0[8*s2+0], s0[8*s2+1]);
          unsigned a1 = pack2bf(s0[8*s2+2], s0[8*s2+3]);
          unsigned b0 = pack2bf(s0[8*s2+4], s0[8*s2+5]);
          unsigned b1 = pack2bf(s0[8*s2+6], s0[8*s2+7]);
          i32x2 r0 = __builtin_amdgcn_permlane32_swap((int)a0, (int)b0, false, false);
          i32x2 r1 = __builtin_amdgcn_permlane32_swap((int)a1, (int)b1, false, false);
          union { int u[4]; bf16x8 v; } pw;
          pw.u[0] = r0.x; pw.u[1] = r1.x; pw.u[2] = r0.y; pw.u[3] = r1.y;
          pf[s2] = pw.v;
        }
        {
          unsigned a0 = pack2bf(s1[8*s2+0], s1[8*s2+1]);
          unsigned a1 = pack2bf(s1[8*s2+2], s1[8*s2+3]);
          unsigned b0 = pack2bf(s1[8*s2+4], s1[8*s2+5]);
          unsigned b1 = pack2bf(s1[8*s2+6], s1[8*s2+7]);
          i32x2 r0 = __builtin_amdgcn_permlane32_swap((int)a0, (int)b0, false, false);
          i32x2 r1 = __builtin_amdgcn_permlane32_swap((int)a1, (int)b1, false, false);
          union { int u[4]; bf16x8 v; } pw;
          pw.u[0] = r0.x; pw.u[1] = r1.x; pw.u[2] = r0.y; pw.u[3] = r1.y;
          pf[2 + s2] = pw.v;
        }
      }
    }

    __syncthreads();            // barrier1: K(t+1) resident in sC; K(t) dead
    if (have_next) STAGE_V(t + 1, sA);

    if (act) {
      // ---- O^T += V^T P^T: 4 d-blocks x 4 K-steps (r14-verified) ----
      __builtin_amdgcn_s_setprio(1);
      #pragma unroll
      for (int s = 0; s < 4; ++s) {
        int colb = 32 * s + 16 * hi;
        #pragma unroll
        for (int db = 0; db < 4; ++db) {
          int dd = db * 32 + q31;
          bf16x8 vf = *(const bf16x8*)(sB + (dd << 7) + (colb ^ ((dd & 7) << 4)));
          o[db] = __builtin_amdgcn_mfma_f32_32x32x16_bf16(vf, pf[s], o[db], 0, 0, 0);
        }
      }
      __builtin_amdgcn_s_setprio(0);
    }

    __syncthreads();            // barrier2: V(t+1) resident in sA
    unsigned char* nA = sC;     // K(t+1)
    unsigned char* nB = sA;     // V(t+1)
    unsigned char* nC = sB;     // free
    sA = nA; sB = nB; sC = nC;
  }

  // ---- epilogue: O /= l, float4 stores (r14-verified mapping) ----
  float inv = 1.f / lrow;
  float* obase = out + (size_t)myq * ODIM + h * HD;
  #pragma unroll
  for (int db = 0; db < 4; ++db) {
    #pragma unroll
    for (int c = 0; c < 4; ++c) {
      int d0 = db * 32 + 8 * c + 4 * hi;
      float4 st = {o[db][4*c+0] * inv, o[db][4*c+1] * inv,
                   o[db][4*c+2] * inv, o[db][4*c+3] * inv};
      *(float4*)(obase + d0) = st;
    }
  }
#undef STAGE_K
#undef STAGE_V
}

// ---------- fallback (r12 verbatim): used when ws_size is too small ----------
__global__ __launch_bounds__(512, 4) void sdpa_flash_fb(
    const float* __restrict__ q, const float* __restrict__ k,
    const float* __restrict__ v, float* __restrict__ out) {
  __shared__ __align__(16) unsigned char smem[65536];
  const int tid = threadIdx.x;
  const int w = tid >> 6;
  const int l = tid & 63;
  const int lm = l & 15;
  const int lg = l >> 4;
  const int p = (int)blockIdx.x;
  const int qtA = p;
  const int qtB = 31 - p;
  const int myqt = (w < 4) ? qtA : qtB;
  const int h = (int)blockIdx.y;
  const int hkv = h >> 2;
  const int qbase = myqt * QB + 16 * (w & 3);
  const int myrow = qbase + lm;
  bf16x8 qa[4];
  {
    const float* qr = q + ((size_t)(h * SEQ + myrow)) * HD + 8 * lg;
    #pragma unroll
    for (int c = 0; c < 4; ++c) {
      float4 a = *(const float4*)(qr + 32 * c);
      float4 b = *(const float4*)(qr + 32 * c + 4);
      union { unsigned short hh[8]; bf16x8 vv; } pk;
      pk.hh[0] = f2bf(a.x * SCALE); pk.hh[1] = f2bf(a.y * SCALE);
      pk.hh[2] = f2bf(a.z * SCALE); pk.hh[3] = f2bf(a.w * SCALE);
      pk.hh[4] = f2bf(b.x * SCALE); pk.hh[5] = f2bf(b.y * SCALE);
      pk.hh[6] = f2bf(b.z * SCALE); pk.hh[7] = f2bf(b.w * SCALE);
      qa[c] = pk.vv;
    }
  }
  f32x4 o[8];
  #pragma unroll
  for (int i = 0; i < 8; ++i) o[i] = (f32x4){0.f, 0.f, 0.f, 0.f};
  float mrow = -1e30f;
  float lrow = 0.f;
  const int ntiles = qtB + 1;
  const float* kg0 = k + (size_t)hkv * SEQ * HD;
  const float* vg0 = v + (size_t)hkv * SEQ * HD;
  const int k_r0 = tid >> 4;
  const int k_c8 = (tid & 15) << 3;
  const int v_rr = (tid & 31) << 1;
  const int v_d0 = (tid >> 5) << 3;
  float4 ka0, kb0, ka1, kb1, va0, vb0, va1, vb1;
#define LOADT(tt) {                                                          \
    const float* kg_ = kg0 + (size_t)((tt) * KVB) * HD + k_r0 * HD + k_c8;   \
    ka0 = *(const float4*)(kg_);                                             \
    kb0 = *(const float4*)(kg_ + 4);                                         \
    ka1 = *(const float4*)(kg_ + 32 * HD);                                   \
    kb1 = *(const float4*)(kg_ + 32 * HD + 4);                               \
    const float* vg_ = vg0 + (size_t)((tt) * KVB) * HD + v_rr * HD + v_d0;   \
    va0 = *(const float4*)(vg_);                                             \
    vb0 = *(const float4*)(vg_ + 4);                                         \
    va1 = *(const float4*)(vg_ + HD);                                        \
    vb1 = *(const float4*)(vg_ + HD + 4);                                    \
  }
#define WRITELDS(bufbase) {                                                  \
    unsigned char* Kb_ = (bufbase);                                          \
    unsigned char* Vb_ = (bufbase) + 16384;                                  \
    {                                                                        \
      union { unsigned short hh[8]; uint4 u4; } pk_;                         \
      pk_.hh[0]=f2bf(ka0.x); pk_.hh[1]=f2bf(ka0.y);                          \
      pk_.hh[2]=f2bf(ka0.z); pk_.hh[3]=f2bf(ka0.w);                          \
      pk_.hh[4]=f2bf(kb0.x); pk_.hh[5]=f2bf(kb0.y);                          \
      pk_.hh[6]=f2bf(kb0.z); pk_.hh[7]=f2bf(kb0.w);                          \
      int byte_ = (k_r0 << 8) + ((k_c8 << 1) ^ ((k_r0 & 7) << 4));           \
      *(uint4*)(Kb_ + byte_) = pk_.u4;                                       \
    }                                                                        \
    {                                                                        \
      int r1_ = k_r0 + 32;                                                   \
      union { unsigned short hh[8]; uint4 u4; } pk_;                         \
      pk_.hh[0]=f2bf(ka1.x); pk_.hh[1]=f2bf(ka1.y);                          \
      pk_.hh[2]=f2bf(ka1.z); pk_.hh[3]=f2bf(ka1.w);                          \
      pk_.hh[4]=f2bf(kb1.x); pk_.hh[5]=f2bf(kb1.y);                          \
      pk_.hh[6]=f2bf(kb1.z); pk_.hh[7]=f2bf(kb1.w);                          \
      int byte_ = (r1_ << 8) + ((k_c8 << 1) ^ ((r1_ & 7) << 4));             \
      *(uint4*)(Kb_ + byte_) = pk_.u4;                                       \
    }                                                                        \
    {                                                                        \
      unsigned w0_ = pack2bf(va0.x, va1.x), w1_ = pack2bf(va0.y, va1.y);     \
      unsigned w2_ = pack2bf(va0.z, va1.z), w3_ = pack2bf(va0.w, va1.w);     \
      unsigned w4_ = pack2bf(vb0.x, vb1.x), w5_ = pack2bf(vb0.y, vb1.y);     \
      unsigned w6_ = pack2bf(vb0.z, vb1.z), w7_ = pack2bf(vb0.w, vb1.w);     \
      int rb_ = v_rr << 1;                                                   \
      int d_;                                                                \
      d_ = v_d0;     *(unsigned*)(Vb_ + (d_ << 7) + (rb_ ^ ((d_ & 7) << 4))) = w0_; \
      d_ = v_d0 + 1; *(unsigned*)(Vb_ + (d_ << 7) + (rb_ ^ ((d_ & 7) << 4))) = w1_; \
      d_ = v_d0 + 2; *(unsigned*)(Vb_ + (d_ << 7) + (rb_ ^ ((d_ & 7) << 4))) = w2_; \
      d_ = v_d0 + 3; *(unsigned*)(Vb_ + (d_ << 7) + (rb_ ^ ((d_ & 7) << 4))) = w3_; \
      d_ = v_d0 + 4; *(unsigned*)(Vb_ + (d_ << 7) + (rb_ ^ ((d_ & 7) << 4))) = w4_; \
      d_ = v_d0 + 5; *(unsigned*)(Vb_ + (d_ << 7) + (rb_ ^ ((d_ & 7) << 4))) = w5_; \
      d_ = v_d0 + 6; *(unsigned*)(Vb_ + (d_ << 7) + (rb_ ^ ((d_ & 7) << 4))) = w6_; \
      d_ = v_d0 + 7; *(unsigned*)(Vb_ + (d_ << 7) + (rb_ ^ ((d_ & 7) << 4))) = w7_; \
    }                                                                        \
  }
  LOADT(0);
  WRITELDS(smem);
  __syncthreads();
  int cur = 0;
  for (int t = 0; t < ntiles; ++t) {
    const int kv0 = t * KVB;
    const bool have_next = (t + 1 < ntiles);
    if (have_next) LOADT(t + 1);
    unsigned char* Klds = smem + (cur << 15);
    unsigned char* Vlds = Klds + 16384;
    if (t <= myqt) {
      f32x4 s[4];
      #pragma unroll
      for (int nt = 0; nt < 4; ++nt) s[nt] = (f32x4){0.f, 0.f, 0.f, 0.f};
      #pragma unroll
      for (int nt = 0; nt < 4; ++nt) {
        int r = (nt << 4) + lm;
        #pragma unroll
        for (int kc = 0; kc < 4; ++kc) {
          int byte = (r << 8) + (((kc << 6) + (lg << 4)) ^ ((r & 7) << 4));
          bf16x8 kb = *(const bf16x8*)(Klds + byte);
          s[nt] = __builtin_amdgcn_mfma_f32_16x16x32_bf16(kb, qa[kc], s[nt], 0, 0, 0);
        }
      }
      if (kv0 + KVB - 1 > qbase) {
        #pragma unroll
        for (int nt = 0; nt < 4; ++nt) {
          #pragma unroll
          for (int i = 0; i < 4; ++i) {
            int col = kv0 + (nt << 4) + (lg << 2) + i;
            s[nt][i] += (col > myrow) ? NEGBIG : 0.f;
          }
        }
      }
      float tm = -1e30f;
      #pragma unroll
      for (int nt = 0; nt < 4; ++nt)
        #pragma unroll
        for (int i = 0; i < 4; ++i) tm = fmaxf(tm, s[nt][i]);
      tm = fmaxf(tm, __shfl_xor(tm, 16));
      tm = fmaxf(tm, __shfl_xor(tm, 32));
      float mn = fmaxf(mrow, tm);
      float fac = __expf(mrow - mn);
      mrow = mn;
      float rs = 0.f;
      #pragma unroll
      for (int nt = 0; nt < 4; ++nt) {
        #pragma unroll
        for (int i = 0; i < 4; ++i) {
          float pv = __expf(s[nt][i] - mn);
          s[nt][i] = pv;
          rs += pv;
        }
      }
      rs += __shfl_xor(rs, 16);
      rs += __shfl_xor(rs, 32);
      lrow = lrow * fac + rs;
      #pragma unroll
      for (int nt2 = 0; nt2 < 8; ++nt2) {
        #pragma unroll
        for (int i = 0; i < 4; ++i) o[nt2][i] *= fac;
      }
      unsigned pk0[4], pk1[4];
      #pragma unroll
      for (int nt = 0; nt < 4; ++nt) {
        pk0[nt] = pack2bf(s[nt][0], s[nt][1]);
        pk1[nt] = pack2bf(s[nt][2], s[nt][3]);
      }
      const int srcA = lm + ((lg & 1) << 5);
      const int srcB = srcA + 16;
      const bool lo2 = (lg < 2);
      bf16x8 pb[2];
      #pragma unroll
      for (int kc = 0; kc < 2; ++kc) {
        int a0 = __shfl((int)pk0[2*kc], srcA), b0 = __shfl((int)pk0[2*kc+1], srcA);
        int a1 = __shfl((int)pk1[2*kc], srcA), b1 = __shfl((int)pk1[2*kc+1], srcA);
        int a2 = __shfl((int)pk0[2*kc], srcB), b2 = __shfl((int)pk0[2*kc+1], srcB);
        int a3 = __shfl((int)pk1[2*kc], srcB), b3 = __shfl((int)pk1[2*kc+1], srcB);
        union { int uu[4]; bf16x8 v; } pw;
        pw.uu[0] = lo2 ? a0 : b0;
        pw.uu[1] = lo2 ? a1 : b1;
        pw.uu[2] = lo2 ? a2 : b2;
        pw.uu[3] = lo2 ? a3 : b3;
        pb[kc] = pw.v;
      }
      #pragma unroll
      for (int nt2 = 0; nt2 < 8; ++nt2) {
        int dr = (nt2 << 4) + lm;
        #pragma unroll
        for (int kc = 0; kc < 2; ++kc) {
          int byte = (dr << 7) + (((kc << 6) + (lg << 4)) ^ ((dr & 7) << 4));
          bf16x8 vb = *(const bf16x8*)(Vlds + byte);
          o[nt2] = __builtin_amdgcn_mfma_f32_16x16x32_bf16(vb, pb[kc], o[nt2], 0, 0, 0);
        }
      }
    }
    if (have_next) {
      WRITELDS(smem + ((cur ^ 1) << 15));
    }
    __syncthreads();
    cur ^= 1;
  }
  float inv = 1.f / lrow;
  float* orow = out + (size_t)myrow * ODIM + h * HD + (lg << 2);
  #pragma unroll
  for (int nt2 = 0; nt2 < 8; ++nt2) {
    float4 st = {o[nt2][0] * inv, o[nt2][1] * inv, o[nt2][2] * inv, o[nt2][3] * inv};
    *(float4*)(orow + (nt2 << 4)) = st;
  }
#undef LOADT
#undef WRITELDS
}

extern "C" void kernel_launch(void* const* d_in, const int* in_sizes, int n_in,
                              void* d_out, int out_size, void* d_ws, size_t ws_size,
                              hipStream_t stream) {
  const float* q = (const float*)d_in[1];
  const float* k = (const float*)d_in[2];
  const float* v = (const float*)d_in[3];
  float* out = (float*)d_out;
  const size_t need = (size_t)(NKV * 32 * 16384) * 2;  // 8 MB K+V images
  if (ws_size >= need && d_ws != nullptr) {
    unsigned char* ws = (unsigned char*)d_ws;
    int total = KWORK + VWORK;
    sdpa_prepass<<<(total + 255) / 256, 256, 0, stream>>>(k, v, ws);
    dim3 grid(SEQ / QB / 2, NH);  // 16 balanced pairs x 32 heads, 256-thr blocks
    sdpa_flash_kernel<<<grid, 256, 0, stream>>>(
        q, ws, ws + (NKV * 32 * 16384), out);
  } else {
    dim3 gridf(SEQ / QB / 2, NH);
    sdpa_flash_fb<<<gridf, 512, 0, stream>>>(q, k, v, out);
  }
}

// Round 25
// 82.393 us; speedup vs baseline: 1.0770x; 1.0770x over previous
//
#include <hip/hip_runtime.h>
#include <hip/hip_bf16.h>

#define SEQ 2048
#define HD 128
#define NH 32
#define NKV 8
#define ODIM 4096
#define QB 64
#define KVB 64
#define SCALE 0.08838834764831845f
#define SCALE_L2E 0.12752767f   /* SCALE * log2(e) */
#define NEGBIG -1e9f
#define NEGBIG_L2 -1.4426950e9f
#define THR_L2 11.54f

typedef __attribute__((ext_vector_type(8))) short bf16x8;
typedef __attribute__((ext_vector_type(4))) float f32x4;

__device__ __forceinline__ unsigned short f2bf(float x) {
  union { __hip_bfloat16 b; unsigned short u; } c;
  c.b = __float2bfloat16(x);
  return c.u;
}

__device__ __forceinline__ unsigned pack2bf(float lo, float hi) {
  union { __hip_bfloat162 h; unsigned u; } c;
  c.h = __float22bfloat162_rn(float2{lo, hi});
  return c.u;
}

__device__ __forceinline__ void gload_lds16(const unsigned char* g, unsigned char* l) {
  __builtin_amdgcn_global_load_lds(
      (const __attribute__((address_space(1))) void*)g,
      (__attribute__((address_space(3))) void*)l, 16, 0, 0);
}

// ---------- prepass: K/V f32 -> pre-swizzled bf16 tile images in d_ws ----------
#define KWORK (NKV * SEQ * 16)
#define VWORK (NKV * (SEQ / 2) * 16)
__global__ __launch_bounds__(256) void sdpa_prepass(
    const float* __restrict__ k, const float* __restrict__ v,
    unsigned char* __restrict__ ws) {
  unsigned char* kimg = ws;
  unsigned char* vimg = ws + (NKV * 32 * 16384);
  int idx = (int)blockIdx.x * 256 + (int)threadIdx.x;
  if (idx < KWORK) {
    int hkv = idx >> 15;
    int rem = idx & 32767;
    int rg = rem >> 4;
    int c8 = (rem & 15) << 3;
    const float* src = k + ((size_t)hkv * SEQ + rg) * HD + c8;
    float4 a = *(const float4*)(src);
    float4 b = *(const float4*)(src + 4);
    union { unsigned short hh[8]; uint4 u4; } pk;
    pk.hh[0]=f2bf(a.x); pk.hh[1]=f2bf(a.y); pk.hh[2]=f2bf(a.z); pk.hh[3]=f2bf(a.w);
    pk.hh[4]=f2bf(b.x); pk.hh[5]=f2bf(b.y); pk.hh[6]=f2bf(b.z); pk.hh[7]=f2bf(b.w);
    int t = rg >> 6, r = rg & 63;
    size_t base = ((size_t)(hkv * 32 + t)) << 14;
    *(uint4*)(kimg + base + (r << 8) + ((c8 << 1) ^ ((r & 7) << 4))) = pk.u4;
  } else {
    int u = idx - KWORK;
    if (u >= VWORK) return;
    int hkv = u >> 14;
    int rem = u & 16383;
    int pr = rem >> 4;
    int d0 = (rem & 15) << 3;
    int rg = pr << 1;
    const float* s0 = v + ((size_t)hkv * SEQ + rg) * HD + d0;
    const float* s1 = s0 + HD;
    float4 a0 = *(const float4*)(s0);
    float4 b0 = *(const float4*)(s0 + 4);
    float4 a1 = *(const float4*)(s1);
    float4 b1 = *(const float4*)(s1 + 4);
    float lo[8] = {a0.x,a0.y,a0.z,a0.w,b0.x,b0.y,b0.z,b0.w};
    float hi[8] = {a1.x,a1.y,a1.z,a1.w,b1.x,b1.y,b1.z,b1.w};
    int t = rg >> 6, rr = rg & 63;
    size_t base = ((size_t)(hkv * 32 + t)) << 14;
    int rb = rr << 1;
    #pragma unroll
    for (int j = 0; j < 8; ++j) {
      int d = d0 + j;
      *(unsigned*)(vimg + base + (d << 7) + (rb ^ ((d & 7) << 4))) =
          pack2bf(lo[j], hi[j]);
    }
  }
}

// ---------- main: 3-slot K/V rotation, 48KB LDS (r20 best: 82.7us) ----------
// Per tile: issue K(t+1)->C ; QK+mask+softmax+P-build (reg-only) ; barrier1 ;
// issue V(t+1)->A (K(t) dead) ; PV from B ; barrier2 ; rotate.
// Only pb[2] (8 VGPR) lives across barrier1.
__global__ __launch_bounds__(512, 4) void sdpa_flash_kernel(
    const float* __restrict__ q, const unsigned char* __restrict__ kimg,
    const unsigned char* __restrict__ vimg, float* __restrict__ out) {
  __shared__ __align__(16) unsigned char smem[49152];
  const int tid = threadIdx.x;
  const int w = tid >> 6;
  const int l = tid & 63;
  const int lm = l & 15;
  const int lg = l >> 4;

  const int p = (int)blockIdx.x;
  const int qtA = p;
  const int qtB = 31 - p;
  const int myqt = (w < 4) ? qtA : qtB;
  const int h = (int)blockIdx.y;
  const int hkv = h >> 2;
  const int qbase = myqt * QB + 16 * (w & 3);
  const int myrow = qbase + lm;

  // Q pre-scaled by SCALE*log2(e): exp2 softmax
  bf16x8 qa[4];
  {
    const float* qr = q + ((size_t)(h * SEQ + myrow)) * HD + 8 * lg;
    #pragma unroll
    for (int c = 0; c < 4; ++c) {
      float4 a = *(const float4*)(qr + 32 * c);
      float4 b = *(const float4*)(qr + 32 * c + 4);
      union { unsigned short hh[8]; bf16x8 vv; } pk;
      pk.hh[0] = f2bf(a.x * SCALE_L2E); pk.hh[1] = f2bf(a.y * SCALE_L2E);
      pk.hh[2] = f2bf(a.z * SCALE_L2E); pk.hh[3] = f2bf(a.w * SCALE_L2E);
      pk.hh[4] = f2bf(b.x * SCALE_L2E); pk.hh[5] = f2bf(b.y * SCALE_L2E);
      pk.hh[6] = f2bf(b.z * SCALE_L2E); pk.hh[7] = f2bf(b.w * SCALE_L2E);
      qa[c] = pk.vv;
    }
  }

  f32x4 o[8];
  #pragma unroll
  for (int i = 0; i < 8; ++i) o[i] = (f32x4){0.f, 0.f, 0.f, 0.f};
  float mrow = -1e30f;
  float lrow = 0.f;

  const int ntiles = qtB + 1;
  const unsigned char* kt0 = kimg + (((size_t)(hkv * 32)) << 14);
  const unsigned char* vt0 = vimg + (((size_t)(hkv * 32)) << 14);
  const int woff = w << 10;

#define STAGE_K(tt, Kb) {                                                    \
    const unsigned char* ks_ = kt0 + (((size_t)(tt)) << 14);                 \
    gload_lds16(ks_ + woff + (l << 4), (Kb) + woff);                         \
    gload_lds16(ks_ + 8192 + woff + (l << 4), (Kb) + 8192 + woff);           \
  }
#define STAGE_V(tt, Vb) {                                                    \
    const unsigned char* vs_ = vt0 + (((size_t)(tt)) << 14);                 \
    gload_lds16(vs_ + woff + (l << 4), (Vb) + woff);                         \
    gload_lds16(vs_ + 8192 + woff + (l << 4), (Vb) + 8192 + woff);           \
  }

  unsigned char* sA = smem;            // K(t)
  unsigned char* sB = smem + 16384;    // V(t)
  unsigned char* sC = smem + 32768;    // free / incoming K(t+1)

  // prologue: stage tile 0
  STAGE_K(0, sA);
  STAGE_V(0, sB);
  __syncthreads();

  for (int t = 0; t < ntiles; ++t) {
    const int kv0 = t * KVB;
    const bool have_next = (t + 1 < ntiles);
    if (have_next) STAGE_K(t + 1, sC);

    const bool act = (t <= myqt);
    bf16x8 pb[2];
    if (act) {
      // ---- QK from sA ----
      f32x4 s[4];
      #pragma unroll
      for (int nt = 0; nt < 4; ++nt) s[nt] = (f32x4){0.f, 0.f, 0.f, 0.f};
      __builtin_amdgcn_s_setprio(1);
      #pragma unroll
      for (int nt = 0; nt < 4; ++nt) {
        int r = (nt << 4) + lm;
        #pragma unroll
        for (int kc = 0; kc < 4; ++kc) {
          int byte = (r << 8) + (((kc << 6) + (lg << 4)) ^ ((r & 7) << 4));
          bf16x8 kb = *(const bf16x8*)(sA + byte);
          s[nt] = __builtin_amdgcn_mfma_f32_16x16x32_bf16(kb, qa[kc], s[nt], 0, 0, 0);
        }
      }
      __builtin_amdgcn_s_setprio(0);

      if (kv0 + KVB - 1 > qbase) {
        #pragma unroll
        for (int nt = 0; nt < 4; ++nt) {
          #pragma unroll
          for (int i = 0; i < 4; ++i) {
            int col = kv0 + (nt << 4) + (lg << 2) + i;
            s[nt][i] += (col > myrow) ? NEGBIG_L2 : 0.f;
          }
        }
      }

      // ---- online softmax (log2 domain), defer-max rescale ----
      float tm = -1e30f;
      #pragma unroll
      for (int nt = 0; nt < 4; ++nt)
        #pragma unroll
        for (int i = 0; i < 4; ++i) tm = fmaxf(tm, s[nt][i]);
      tm = fmaxf(tm, __shfl_xor(tm, 16));
      tm = fmaxf(tm, __shfl_xor(tm, 32));
      if (!__all(tm <= mrow + THR_L2)) {
        float mn = fmaxf(mrow, tm);
        float fac = __builtin_amdgcn_exp2f(mrow - mn);
        mrow = mn;
        lrow *= fac;
        #pragma unroll
        for (int nt2 = 0; nt2 < 8; ++nt2) {
          #pragma unroll
          for (int i = 0; i < 4; ++i) o[nt2][i] *= fac;
        }
      }
      float rs = 0.f;
      #pragma unroll
      for (int nt = 0; nt < 4; ++nt) {
        #pragma unroll
        for (int i = 0; i < 4; ++i) {
          float pv = __builtin_amdgcn_exp2f(s[nt][i] - mrow);
          s[nt][i] = pv;
          rs += pv;
        }
      }
      rs += __shfl_xor(rs, 16);
      rs += __shfl_xor(rs, 32);
      lrow += rs;

      // ---- P B-frags (register-only) ----
      unsigned pk0[4], pk1[4];
      #pragma unroll
      for (int nt = 0; nt < 4; ++nt) {
        pk0[nt] = pack2bf(s[nt][0], s[nt][1]);
        pk1[nt] = pack2bf(s[nt][2], s[nt][3]);
      }
      const int srcA = lm + ((lg & 1) << 5);
      const int srcB = srcA + 16;
      const bool lo2 = (lg < 2);
      #pragma unroll
      for (int kc = 0; kc < 2; ++kc) {
        int a0 = __shfl((int)pk0[2*kc], srcA), b0 = __shfl((int)pk0[2*kc+1], srcA);
        int a1 = __shfl((int)pk1[2*kc], srcA), b1 = __shfl((int)pk1[2*kc+1], srcA);
        int a2 = __shfl((int)pk0[2*kc], srcB), b2 = __shfl((int)pk0[2*kc+1], srcB);
        int a3 = __shfl((int)pk1[2*kc], srcB), b3 = __shfl((int)pk1[2*kc+1], srcB);
        union { int uu[4]; bf16x8 v; } pw;
        pw.uu[0] = lo2 ? a0 : b0;
        pw.uu[1] = lo2 ? a1 : b1;
        pw.uu[2] = lo2 ? a2 : b2;
        pw.uu[3] = lo2 ? a3 : b3;
        pb[kc] = pw.v;
      }
    }

    __syncthreads();            // barrier1: K(t+1) resident in sC; K(t) dead
    if (have_next) STAGE_V(t + 1, sA);

    if (act) {
      // ---- O^T += V^T P^T from sB ----
      __builtin_amdgcn_s_setprio(1);
      #pragma unroll
      for (int nt2 = 0; nt2 < 8; ++nt2) {
        int dr = (nt2 << 4) + lm;
        #pragma unroll
        for (int kc = 0; kc < 2; ++kc) {
          int byte = (dr << 7) + (((kc << 6) + (lg << 4)) ^ ((dr & 7) << 4));
          bf16x8 vb = *(const bf16x8*)(sB + byte);
          o[nt2] = __builtin_amdgcn_mfma_f32_16x16x32_bf16(vb, pb[kc], o[nt2], 0, 0, 0);
        }
      }
      __builtin_amdgcn_s_setprio(0);
    }

    __syncthreads();            // barrier2: V(t+1) resident in sA
    unsigned char* nA = sC;     // K(t+1)
    unsigned char* nB = sA;     // V(t+1)
    unsigned char* nC = sB;     // free
    sA = nA; sB = nB; sC = nC;
  }

  float inv = 1.f / lrow;
  float* orow = out + (size_t)myrow * ODIM + h * HD + (lg << 2);
  #pragma unroll
  for (int nt2 = 0; nt2 < 8; ++nt2) {
    float4 st = {o[nt2][0] * inv, o[nt2][1] * inv, o[nt2][2] * inv, o[nt2][3] * inv};
    *(float4*)(orow + (nt2 << 4)) = st;
  }
#undef STAGE_K
#undef STAGE_V
}

// ---------- fallback (r12 verbatim): used when ws_size is too small ----------
__global__ __launch_bounds__(512, 4) void sdpa_flash_fb(
    const float* __restrict__ q, const float* __restrict__ k,
    const float* __restrict__ v, float* __restrict__ out) {
  __shared__ __align__(16) unsigned char smem[65536];
  const int tid = threadIdx.x;
  const int w = tid >> 6;
  const int l = tid & 63;
  const int lm = l & 15;
  const int lg = l >> 4;
  const int p = (int)blockIdx.x;
  const int qtA = p;
  const int qtB = 31 - p;
  const int myqt = (w < 4) ? qtA : qtB;
  const int h = (int)blockIdx.y;
  const int hkv = h >> 2;
  const int qbase = myqt * QB + 16 * (w & 3);
  const int myrow = qbase + lm;
  bf16x8 qa[4];
  {
    const float* qr = q + ((size_t)(h * SEQ + myrow)) * HD + 8 * lg;
    #pragma unroll
    for (int c = 0; c < 4; ++c) {
      float4 a = *(const float4*)(qr + 32 * c);
      float4 b = *(const float4*)(qr + 32 * c + 4);
      union { unsigned short hh[8]; bf16x8 vv; } pk;
      pk.hh[0] = f2bf(a.x * SCALE); pk.hh[1] = f2bf(a.y * SCALE);
      pk.hh[2] = f2bf(a.z * SCALE); pk.hh[3] = f2bf(a.w * SCALE);
      pk.hh[4] = f2bf(b.x * SCALE); pk.hh[5] = f2bf(b.y * SCALE);
      pk.hh[6] = f2bf(b.z * SCALE); pk.hh[7] = f2bf(b.w * SCALE);
      qa[c] = pk.vv;
    }
  }
  f32x4 o[8];
  #pragma unroll
  for (int i = 0; i < 8; ++i) o[i] = (f32x4){0.f, 0.f, 0.f, 0.f};
  float mrow = -1e30f;
  float lrow = 0.f;
  const int ntiles = qtB + 1;
  const float* kg0 = k + (size_t)hkv * SEQ * HD;
  const float* vg0 = v + (size_t)hkv * SEQ * HD;
  const int k_r0 = tid >> 4;
  const int k_c8 = (tid & 15) << 3;
  const int v_rr = (tid & 31) << 1;
  const int v_d0 = (tid >> 5) << 3;
  float4 ka0, kb0, ka1, kb1, va0, vb0, va1, vb1;
#define LOADT(tt) {                                                          \
    const float* kg_ = kg0 + (size_t)((tt) * KVB) * HD + k_r0 * HD + k_c8;   \
    ka0 = *(const float4*)(kg_);                                             \
    kb0 = *(const float4*)(kg_ + 4);                                         \
    ka1 = *(const float4*)(kg_ + 32 * HD);                                   \
    kb1 = *(const float4*)(kg_ + 32 * HD + 4);                               \
    const float* vg_ = vg0 + (size_t)((tt) * KVB) * HD + v_rr * HD + v_d0;   \
    va0 = *(const float4*)(vg_);                                             \
    vb0 = *(const float4*)(vg_ + 4);                                         \
    va1 = *(const float4*)(vg_ + HD);                                        \
    vb1 = *(const float4*)(vg_ + HD + 4);                                    \
  }
#define WRITELDS(bufbase) {                                                  \
    unsigned char* Kb_ = (bufbase);                                          \
    unsigned char* Vb_ = (bufbase) + 16384;                                  \
    {                                                                        \
      union { unsigned short hh[8]; uint4 u4; } pk_;                         \
      pk_.hh[0]=f2bf(ka0.x); pk_.hh[1]=f2bf(ka0.y);                          \
      pk_.hh[2]=f2bf(ka0.z); pk_.hh[3]=f2bf(ka0.w);                          \
      pk_.hh[4]=f2bf(kb0.x); pk_.hh[5]=f2bf(kb0.y);                          \
      pk_.hh[6]=f2bf(kb0.z); pk_.hh[7]=f2bf(kb0.w);                          \
      int byte_ = (k_r0 << 8) + ((k_c8 << 1) ^ ((k_r0 & 7) << 4));           \
      *(uint4*)(Kb_ + byte_) = pk_.u4;                                       \
    }                                                                        \
    {                                                                        \
      int r1_ = k_r0 + 32;                                                   \
      union { unsigned short hh[8]; uint4 u4; } pk_;                         \
      pk_.hh[0]=f2bf(ka1.x); pk_.hh[1]=f2bf(ka1.y);                          \
      pk_.hh[2]=f2bf(ka1.z); pk_.hh[3]=f2bf(ka1.w);                          \
      pk_.hh[4]=f2bf(kb1.x); pk_.hh[5]=f2bf(kb1.y);                          \
      pk_.hh[6]=f2bf(kb1.z); pk_.hh[7]=f2bf(kb1.w);                          \
      int byte_ = (r1_ << 8) + ((k_c8 << 1) ^ ((r1_ & 7) << 4));             \
      *(uint4*)(Kb_ + byte_) = pk_.u4;                                       \
    }                                                                        \
    {                                                                        \
      unsigned w0_ = pack2bf(va0.x, va1.x), w1_ = pack2bf(va0.y, va1.y);     \
      unsigned w2_ = pack2bf(va0.z, va1.z), w3_ = pack2bf(va0.w, va1.w);     \
      unsigned w4_ = pack2bf(vb0.x, vb1.x), w5_ = pack2bf(vb0.y, vb1.y);     \
      unsigned w6_ = pack2bf(vb0.z, vb1.z), w7_ = pack2bf(vb0.w, vb1.w);     \
      int rb_ = v_rr << 1;                                                   \
      int d_;                                                                \
      d_ = v_d0;     *(unsigned*)(Vb_ + (d_ << 7) + (rb_ ^ ((d_ & 7) << 4))) = w0_; \
      d_ = v_d0 + 1; *(unsigned*)(Vb_ + (d_ << 7) + (rb_ ^ ((d_ & 7) << 4))) = w1_; \
      d_ = v_d0 + 2; *(unsigned*)(Vb_ + (d_ << 7) + (rb_ ^ ((d_ & 7) << 4))) = w2_; \
      d_ = v_d0 + 3; *(unsigned*)(Vb_ + (d_ << 7) + (rb_ ^ ((d_ & 7) << 4))) = w3_; \
      d_ = v_d0 + 4; *(unsigned*)(Vb_ + (d_ << 7) + (rb_ ^ ((d_ & 7) << 4))) = w4_; \
      d_ = v_d0 + 5; *(unsigned*)(Vb_ + (d_ << 7) + (rb_ ^ ((d_ & 7) << 4))) = w5_; \
      d_ = v_d0 + 6; *(unsigned*)(Vb_ + (d_ << 7) + (rb_ ^ ((d_ & 7) << 4))) = w6_; \
      d_ = v_d0 + 7; *(unsigned*)(Vb_ + (d_ << 7) + (rb_ ^ ((d_ & 7) << 4))) = w7_; \
    }                                                                        \
  }
  LOADT(0);
  WRITELDS(smem);
  __syncthreads();
  int cur = 0;
  for (int t = 0; t < ntiles; ++t) {
    const int kv0 = t * KVB;
    const bool have_next = (t + 1 < ntiles);
    if (have_next) LOADT(t + 1);
    unsigned char* Klds = smem + (cur << 15);
    unsigned char* Vlds = Klds + 16384;
    if (t <= myqt) {
      f32x4 s[4];
      #pragma unroll
      for (int nt = 0; nt < 4; ++nt) s[nt] = (f32x4){0.f, 0.f, 0.f, 0.f};
      #pragma unroll
      for (int nt = 0; nt < 4; ++nt) {
        int r = (nt << 4) + lm;
        #pragma unroll
        for (int kc = 0; kc < 4; ++kc) {
          int byte = (r << 8) + (((kc << 6) + (lg << 4)) ^ ((r & 7) << 4));
          bf16x8 kb = *(const bf16x8*)(Klds + byte);
          s[nt] = __builtin_amdgcn_mfma_f32_16x16x32_bf16(kb, qa[kc], s[nt], 0, 0, 0);
        }
      }
      if (kv0 + KVB - 1 > qbase) {
        #pragma unroll
        for (int nt = 0; nt < 4; ++nt) {
          #pragma unroll
          for (int i = 0; i < 4; ++i) {
            int col = kv0 + (nt << 4) + (lg << 2) + i;
            s[nt][i] += (col > myrow) ? NEGBIG : 0.f;
          }
        }
      }
      float tm = -1e30f;
      #pragma unroll
      for (int nt = 0; nt < 4; ++nt)
        #pragma unroll
        for (int i = 0; i < 4; ++i) tm = fmaxf(tm, s[nt][i]);
      tm = fmaxf(tm, __shfl_xor(tm, 16));
      tm = fmaxf(tm, __shfl_xor(tm, 32));
      float mn = fmaxf(mrow, tm);
      float fac = __expf(mrow - mn);
      mrow = mn;
      float rs = 0.f;
      #pragma unroll
      for (int nt = 0; nt < 4; ++nt) {
        #pragma unroll
        for (int i = 0; i < 4; ++i) {
          float pv = __expf(s[nt][i] - mn);
          s[nt][i] = pv;
          rs += pv;
        }
      }
      rs += __shfl_xor(rs, 16);
      rs += __shfl_xor(rs, 32);
      lrow = lrow * fac + rs;
      #pragma unroll
      for (int nt2 = 0; nt2 < 8; ++nt2) {
        #pragma unroll
        for (int i = 0; i < 4; ++i) o[nt2][i] *= fac;
      }
      unsigned pk0[4], pk1[4];
      #pragma unroll
      for (int nt = 0; nt < 4; ++nt) {
        pk0[nt] = pack2bf(s[nt][0], s[nt][1]);
        pk1[nt] = pack2bf(s[nt][2], s[nt][3]);
      }
      const int srcA = lm + ((lg & 1) << 5);
      const int srcB = srcA + 16;
      const bool lo2 = (lg < 2);
      bf16x8 pb[2];
      #pragma unroll
      for (int kc = 0; kc < 2; ++kc) {
        int a0 = __shfl((int)pk0[2*kc], srcA), b0 = __shfl((int)pk0[2*kc+1], srcA);
        int a1 = __shfl((int)pk1[2*kc], srcA), b1 = __shfl((int)pk1[2*kc+1], srcA);
        int a2 = __shfl((int)pk0[2*kc], srcB), b2 = __shfl((int)pk0[2*kc+1], srcB);
        int a3 = __shfl((int)pk1[2*kc], srcB), b3 = __shfl((int)pk1[2*kc+1], srcB);
        union { int uu[4]; bf16x8 v; } pw;
        pw.uu[0] = lo2 ? a0 : b0;
        pw.uu[1] = lo2 ? a1 : b1;
        pw.uu[2] = lo2 ? a2 : b2;
        pw.uu[3] = lo2 ? a3 : b3;
        pb[kc] = pw.v;
      }
      #pragma unroll
      for (int nt2 = 0; nt2 < 8; ++nt2) {
        int dr = (nt2 << 4) + lm;
        #pragma unroll
        for (int kc = 0; kc < 2; ++kc) {
          int byte = (dr << 7) + (((kc << 6) + (lg << 4)) ^ ((dr & 7) << 4));
          bf16x8 vb = *(const bf16x8*)(Vlds + byte);
          o[nt2] = __builtin_amdgcn_mfma_f32_16x16x32_bf16(vb, pb[kc], o[nt2], 0, 0, 0);
        }
      }
    }
    if (have_next) {
      WRITELDS(smem + ((cur ^ 1) << 15));
    }
    __syncthreads();
    cur ^= 1;
  }
  float inv = 1.f / lrow;
  float* orow = out + (size_t)myrow * ODIM + h * HD + (lg << 2);
  #pragma unroll
  for (int nt2 = 0; nt2 < 8; ++nt2) {
    float4 st = {o[nt2][0] * inv, o[nt2][1] * inv, o[nt2][2] * inv, o[nt2][3] * inv};
    *(float4*)(orow + (nt2 << 4)) = st;
  }
#undef LOADT
#undef WRITELDS
}

extern "C" void kernel_launch(void* const* d_in, const int* in_sizes, int n_in,
                              void* d_out, int out_size, void* d_ws, size_t ws_size,
                              hipStream_t stream) {
  const float* q = (const float*)d_in[1];
  const float* k = (const float*)d_in[2];
  const float* v = (const float*)d_in[3];
  float* out = (float*)d_out;
  dim3 grid(SEQ / QB / 2, NH);  // 16 balanced Q-tile pairs x 32 heads
  const size_t need = (size_t)(NKV * 32 * 16384) * 2;  // 8 MB K+V images
  if (ws_size >= need && d_ws != nullptr) {
    unsigned char* ws = (unsigned char*)d_ws;
    int total = KWORK + VWORK;
    sdpa_prepass<<<(total + 255) / 256, 256, 0, stream>>>(k, v, ws);
    sdpa_flash_kernel<<<grid, 512, 0, stream>>>(
        q, ws, ws + (NKV * 32 * 16384), out);
  } else {
    sdpa_flash_fb<<<grid, 512, 0, stream>>>(q, k, v, out);
  }
}